// Round 1
// baseline (170.509 us; speedup 1.0000x reference)
//
#include <hip/hip_runtime.h>

#define T_DIM 64
#define N_DIM 16
#define C_DIM 256
#define D_OUTC 129
#define NP (N_DIM * C_DIM) /* 4096 (n,c) pairs -> blocks */

// out[t,n,c,d] = w * sum_ch LIFfilt( x[(.-s)%64] )[t],  s = min(round(delay), 63-argmax_t x)
__global__ __launch_bounds__(256) void jeffress_kernel(
    const float* __restrict__ input,        // (T, N, C, 2)
    const float* __restrict__ delay_param,  // (129, 1)
    const float* __restrict__ weight,       // scalar
    const float* __restrict__ u,            // (N, C, 129, 2)
    float* __restrict__ out)                // (T, N, C, 129)
{
    __shared__ float x_lds[2 * 64];        // x[ch][t]
    __shared__ float G[2 * 64 * 64];       // G[ch][t][s]: filtered value at time t for shift s
    __shared__ int   shifts[D_OUTC * 2];   // shifts[d][ch]
    __shared__ int   cap[2];               // 63 - argmax_t

    const int p   = blockIdx.x;            // p = n*256 + c
    const int tid = threadIdx.x;
    const float DECAY = 0.6065306597126334f; // exp(-1/2) rounded to f32, same as reference

    // ---- phase 1: load the two 64-long time series for this (n,c) ----
    if (tid < 128) {
        int ch = tid & 1, t = tid >> 1;
        x_lds[ch * 64 + t] = input[(t * NP + p) * 2 + ch];
    }
    __syncthreads();

    // ---- phase 2: first-occurrence argmax over t per channel ----
    if (tid < 2) {
        const float* xs = &x_lds[tid * 64];
        float best = xs[0];
        int bi = 0;
        for (int t = 1; t < 64; ++t) {
            float v = xs[t];
            if (v > best) { best = v; bi = t; }
        }
        cap[tid] = 63 - bi;
    }
    __syncthreads();

    // ---- phase 3a: per-d effective shifts (stochastic rounding + clamp) ----
    for (int i = tid; i < D_OUTC * 2; i += 256) {
        int d = i >> 1, ch = i & 1;
        float dp = delay_param[d];
        float bd = ch ? fmaxf(-dp, 0.0f) : fmaxf(dp, 0.0f); // relu(cat([dp,-dp]))
        float df = floorf(bd);
        float uu = u[(p * D_OUTC + d) * 2 + ch];
        float r  = (uu < bd - df) ? df + 1.0f : df;
        float s  = fminf(r, (float)cap[ch]);
        shifts[i] = (int)s;
    }
    // ---- phase 3b: LIF recurrence for all 64 shifts, both channels ----
    if (tid < 128) {
        int ch = tid >> 6, s = tid & 63;     // one wave per channel, lane = shift
        const float* xs = &x_lds[ch * 64];
        float* g = &G[ch * 4096];
        float v = 0.0f;
        for (int t = 0; t < 64; ++t) {
            v = v * DECAY + xs[(t - s) & 63]; // circular shifted input
            g[t * 64 + s] = v;                // stride-1 across lanes: conflict-free
        }
    }
    __syncthreads();

    // ---- phase 4: gather + scale + coalesced store (HBM-bound) ----
    const float w = weight[0];
    for (int idx = tid; idx < 64 * D_OUTC; idx += 256) {
        unsigned t = ((unsigned)idx * 130057u) >> 24;  // idx / 129 (exact for idx < 2^15)
        int d = idx - (int)t * 129;
        int s0 = shifts[d * 2 + 0];
        int s1 = shifts[d * 2 + 1];
        float v = G[(int)t * 64 + s0] + G[4096 + (int)t * 64 + s1];
        out[((int)t * NP + p) * D_OUTC + d] = w * v;
    }
}

extern "C" void kernel_launch(void* const* d_in, const int* in_sizes, int n_in,
                              void* d_out, int out_size, void* d_ws, size_t ws_size,
                              hipStream_t stream) {
    const float* input       = (const float*)d_in[0]; // (64,16,256,2)
    const float* delay_param = (const float*)d_in[1]; // (129,1)
    const float* weight      = (const float*)d_in[2]; // scalar
    const float* u           = (const float*)d_in[3]; // (16,256,129,2)
    float* out = (float*)d_out;                       // (64,16,256,129)

    jeffress_kernel<<<NP, 256, 0, stream>>>(input, delay_param, weight, u, out);
}

// Round 2
// 165.081 us; speedup vs baseline: 1.0329x; 1.0329x over previous
//
#include <hip/hip_runtime.h>
#include <hip/hip_bf16.h>

#define T_DIM 64
#define NP 4096      /* N*C = 16*256 (n,c) pairs -> one block each */
#define D_OUTC 129

// out[t,n,c,d] = w * sum_ch LIF( x[(.-s)%64] )[t],  s = min(round(delay), 63-argmax_t x)
// G[ch][t][s] precomputed for all 64 shifts in bf16 (threshold 0.6 allows it).
__global__ __launch_bounds__(256, 8) void jeffress_kernel(
    const float* __restrict__ input,        // (T, N, C, 2)
    const float* __restrict__ delay_param,  // (129, 1)
    const float* __restrict__ weight,       // scalar
    const float* __restrict__ u,            // (N, C, 129, 2)
    float* __restrict__ out)                // (T, N, C, 129)
{
    __shared__ float x_lds[2][64];
    __shared__ __hip_bfloat16 G[2][64 * 64];   // 16 KB: [ch][t][s]
    __shared__ int shifts[D_OUTC];             // s0 | s1<<16
    __shared__ int cap[2];                     // 63 - argmax_t

    const int p   = blockIdx.x;
    const int tid = threadIdx.x;
    const float DECAY = 0.6065306597126334f;   // exp(-1/2), same f32 value as reference

    // ---- phase 1+2 fused: load x, in-wave butterfly argmax (first occurrence) ----
    if (tid < 128) {
        int ch = tid >> 6, t = tid & 63;       // wave 0 = ch0, wave 1 = ch1; lane = t
        float xv = input[(t * NP + p) * 2 + ch];
        x_lds[ch][t] = xv;
        unsigned b = __float_as_uint(xv);
        b ^= (b & 0x80000000u) ? 0xffffffffu : 0x80000000u;  // total order for floats
        unsigned long long key = ((unsigned long long)b << 32) | (unsigned)(63 - t);
        #pragma unroll
        for (int m = 1; m < 64; m <<= 1) {
            unsigned long long o = __shfl_xor(key, m, 64);
            if (o > key) key = o;              // ties -> larger (63-t) -> first t
        }
        if ((tid & 63) == 0) cap[ch] = (int)(key & 0xffffffffull);  // = 63 - argmax
    }
    __syncthreads();

    if (tid < 128) {
        // ---- phase 3b (waves 0-1): LIF recurrence for all 64 shifts ----
        int ch = tid >> 6, s = tid & 63;
        const float* xs = x_lds[ch];
        __hip_bfloat16* g = G[ch];
        float v = 0.0f;
        #pragma unroll 4
        for (int t = 0; t < 64; ++t) {
            v = v * DECAY + xs[(t - s) & 63];  // permutation across lanes: conflict-free
            g[t * 64 + s] = __float2bfloat16(v);
        }
    } else {
        // ---- phase 3a (waves 2-3): per-d shifts (stoch. round + clamp), packed ----
        int c0 = cap[0], c1 = cap[1];
        for (int d = tid - 128; d < D_OUTC; d += 128) {
            float dp = delay_param[d];
            float b0 = fmaxf(dp, 0.0f), b1 = fmaxf(-dp, 0.0f);  // relu(cat([dp,-dp]))
            float2 uu = ((const float2*)u)[p * D_OUTC + d];
            float f0 = floorf(b0), f1 = floorf(b1);
            float r0 = (uu.x < b0 - f0) ? f0 + 1.0f : f0;
            float r1 = (uu.y < b1 - f1) ? f1 + 1.0f : f1;
            int s0 = (int)fminf(r0, (float)c0);
            int s1 = (int)fminf(r1, (float)c1);
            shifts[d] = s0 | (s1 << 16);
        }
    }
    __syncthreads();

    // ---- phase 4: gather + scale + coalesced store (the HBM-bound 135 MB) ----
    const float w = weight[0];
    int d = (tid < D_OUTC) ? tid : tid - D_OUTC;
    int t = (tid < D_OUTC) ? 0 : 1;
    const __hip_bfloat16* G0 = G[0];
    const __hip_bfloat16* G1 = G[1];
    while (t < T_DIM) {
        int sp = shifts[d];
        int s0 = sp & 0xffff, s1 = sp >> 16;
        float v = __bfloat162float(G0[t * 64 + s0]) + __bfloat162float(G1[t * 64 + s1]);
        out[(t * NP + p) * D_OUTC + d] = w * v;
        d += 127; t += 1;                      // idx += 256 without a divide
        if (d >= D_OUTC) { d -= D_OUTC; ++t; }
    }
}

extern "C" void kernel_launch(void* const* d_in, const int* in_sizes, int n_in,
                              void* d_out, int out_size, void* d_ws, size_t ws_size,
                              hipStream_t stream) {
    const float* input       = (const float*)d_in[0]; // (64,16,256,2)
    const float* delay_param = (const float*)d_in[1]; // (129,1)
    const float* weight      = (const float*)d_in[2]; // scalar
    const float* u           = (const float*)d_in[3]; // (16,256,129,2)
    float* out = (float*)d_out;                       // (64,16,256,129)

    jeffress_kernel<<<NP, 256, 0, stream>>>(input, delay_param, weight, u, out);
}